// Round 1
// baseline (283.862 us; speedup 1.0000x reference)
//
#include <hip/hip_runtime.h>
#include <hip/hip_bf16.h>
#include <stdint.h>

// ---------------- common types / helpers ----------------
typedef __attribute__((ext_vector_type(8))) short  bf16x8;   // 8 bf16 in 4 VGPRs
typedef __attribute__((ext_vector_type(4))) float  f32x4;

#define LOG2E 1.4426950408889634f

__device__ __forceinline__ unsigned short f2bf(float f) {
  unsigned int u = __builtin_bit_cast(unsigned int, f);
  u += 0x7fffu + ((u >> 16) & 1u);          // round-to-nearest-even
  return (unsigned short)(u >> 16);
}

// packed 2xfp32 -> 2xbf16 (v_cvt_pk_bf16_f32 on gfx950), returned as u32
__device__ __forceinline__ unsigned int pk2(float a, float b) {
  __hip_bfloat162 h = __float22bfloat162_rn(make_float2(a, b));
  unsigned int u;
  __builtin_memcpy(&u, &h, 4);
  return u;
}

// async global->LDS, 16B per lane. LDS dest = wave-uniform base + lane*16.
__device__ __forceinline__ void async16(const void* g, void* l) {
  __builtin_amdgcn_global_load_lds(
      (const __attribute__((address_space(1))) unsigned int*)g,
      (__attribute__((address_space(3))) unsigned int*)l,
      16, 0, 0);
}

// ---------------- cast all fp32 inputs -> bf16 in one launch ----------------
// x: 2,097,152 float4; weights: 4 x 262,144 float4. Grid 12288 x 256.
__global__ __launch_bounds__(256) void cast_all(
    const float* __restrict__ x,
    const float* __restrict__ Wq, const float* __restrict__ Wk,
    const float* __restrict__ Wv, const float* __restrict__ Wo,
    unsigned short* __restrict__ xb, unsigned short* __restrict__ wqkv,
    unsigned short* __restrict__ wo) {
  int i = blockIdx.x * 256 + threadIdx.x;
  const float* src;
  unsigned short* dst;
  int off;
  if (i < 2097152) {
    src = x; dst = xb; off = i;
  } else {
    int j = i - 2097152;
    int seg = j >> 18; off = j & 262143;
    src = (seg == 0) ? Wq : (seg == 1) ? Wk : (seg == 2) ? Wv : Wo;
    dst = (seg < 3) ? (wqkv + (size_t)seg * 1048576) : wo;
  }
  float4 f = ((const float4*)src)[off];
  uint2 o;
  o.x = pk2(f.x, f.y);
  o.y = pk2(f.z, f.w);
  ((uint2*)dst)[off] = o;
}

// ---------------- QKV GEMM: C[8192,3072] = x_bf16 @ Wqkv^T + bias ----------------
// XCD-swizzled 1D grid (1536): each XCD owns 3 n-tiles -> its 0.75 MB B strip
// stays L2-resident across all 64 m-tiles. Epilogue stages each wave's 64x64 C
// quadrant in private LDS (stride 72), then coalesced 16B stores.
// Q is scaled by 0.125*log2(e): attn then uses exp2() directly.
__global__ __launch_bounds__(256) void gemm_qkv(
    const unsigned short* __restrict__ xb, const unsigned short* __restrict__ wqkv,
    const float* __restrict__ bq, const float* __restrict__ bk, const float* __restrict__ bv,
    unsigned short* __restrict__ qb, unsigned short* __restrict__ kb,
    unsigned short* __restrict__ vb) {
  __shared__ __align__(16) unsigned short As[128 * 32];
  __shared__ __align__(16) unsigned short Bs[128 * 32];
  __shared__ __align__(16) unsigned short epi[4][64 * 72];   // 36 KB, wave-private
  const int bid = blockIdx.x;
  const int xcd = bid & 7, idx = bid >> 3;       // bid%8 ~ XCD round-robin heuristic
  const int nt = xcd * 3 + (idx % 3);            // 24 n-tiles: 3 per XCD
  const int mt = idx / 3;                        // 64 m-tiles
  const int m0 = mt * 128, n0 = nt * 128;
  const int tid = threadIdx.x;
  const int wv = tid >> 6, lane = tid & 63, qq = lane >> 4, ln = lane & 15;
  const int wm = wv & 1, wn = wv >> 1;
  const int K = 1024;

  f32x4 acc[4][4];
#pragma unroll
  for (int i = 0; i < 4; ++i)
#pragma unroll
    for (int j = 0; j < 4; ++j) acc[i][j] = f32x4{0.f, 0.f, 0.f, 0.f};

  for (int k0 = 0; k0 < K; k0 += 32) {
#pragma unroll
    for (int i = 0; i < 2; ++i) {
      int cc = wv * 2 + i;
      int jp = cc * 64 + lane;
      int row = jp >> 2, cp = jp & 3;
      int c = cp ^ ((row >> 1) & 3);
      async16(xb   + (size_t)(m0 + row) * K + k0 + c * 8, As + cc * 512);
      async16(wqkv + (size_t)(n0 + row) * K + k0 + c * 8, Bs + cc * 512);
    }
    __syncthreads();
    bf16x8 af[4], bf[4];
#pragma unroll
    for (int i = 0; i < 4; ++i) {
      int row = wm * 64 + i * 16 + ln;
      af[i] = *(const bf16x8*)(As + row * 32 + (qq ^ ((row >> 1) & 3)) * 8);
    }
#pragma unroll
    for (int j = 0; j < 4; ++j) {
      int row = wn * 64 + j * 16 + ln;
      bf[j] = *(const bf16x8*)(Bs + row * 32 + (qq ^ ((row >> 1) & 3)) * 8);
    }
#pragma unroll
    for (int i = 0; i < 4; ++i)
#pragma unroll
      for (int j = 0; j < 4; ++j)
        acc[i][j] = __builtin_amdgcn_mfma_f32_16x16x32_bf16(af[i], bf[j], acc[i][j], 0, 0, 0);
    __syncthreads();
  }

  const int nblk = n0 >> 10;                           // 0=Q 1=K 2=V (block-uniform)
  const float* bias = (nblk == 0) ? bq : (nblk == 1) ? bk : bv;
  // Q: fold 1/sqrt(64) AND log2(e) so attention can use exp2 directly
  const float scale = (nblk == 0) ? (0.125f * LOG2E) : 1.0f;
  unsigned short* buf = epi[wv];
  const int ncol0 = (n0 & 1023) + wn * 64;             // multiple of 64
  const int head  = ncol0 >> 6;
  const int mbase = m0 + wm * 64;
  const int b     = mbase >> 11, sbase = mbase & 2047;
  unsigned short* dst = (nblk == 0) ? qb : (nblk == 1) ? kb : vb;

  if (nblk != 2) {
    // ---- Q/K: LDS layout [m(s)][n(d)], stride 72 elems ----
#pragma unroll
    for (int j = 0; j < 4; ++j) {
      float bs = bias[ncol0 + j * 16 + ln] * scale;
#pragma unroll
      for (int i = 0; i < 4; ++i)
#pragma unroll
        for (int r = 0; r < 4; ++r)
          buf[(i * 16 + qq * 4 + r) * 72 + j * 16 + ln] = f2bf(acc[i][j][r] * scale + bs);
    }
    unsigned short* gout = dst + (((size_t)(b * 16 + head)) * 2048 + sbase) * 64;
#pragma unroll
    for (int h = 0; h < 2; ++h)
#pragma unroll
      for (int p = 0; p < 4; ++p) {
        int rr = (lane >> 2) + p * 16;
        int c4 = lane & 3;
        ulonglong2 v = *(const ulonglong2*)(buf + rr * 72 + h * 32 + c4 * 8);
        *(ulonglong2*)(gout + (size_t)rr * 64 + h * 32 + c4 * 8) = v;
      }
  } else {
    // ---- V: LDS layout [n(d)][m(s)], stride 72 elems; packed b64 writes ----
#pragma unroll
    for (int j = 0; j < 4; ++j) {
      float bs = bias[ncol0 + j * 16 + ln];
#pragma unroll
      for (int i = 0; i < 4; ++i) {
        uint2 pk;
        pk.x = pk2(acc[i][j][0] + bs, acc[i][j][1] + bs);
        pk.y = pk2(acc[i][j][2] + bs, acc[i][j][3] + bs);
        *(uint2*)(buf + (j * 16 + ln) * 72 + i * 16 + qq * 4) = pk;
      }
    }
    unsigned short* gout = dst + ((size_t)(b * 16 + head)) * 64 * 2048 + sbase;
#pragma unroll
    for (int p = 0; p < 8; ++p) {
      int dr = (lane >> 3) + p * 8;
      int c8 = lane & 7;
      ulonglong2 v = *(const ulonglong2*)(buf + dr * 72 + c8 * 8);
      *(ulonglong2*)(gout + (size_t)dr * 2048 + c8 * 8) = v;
    }
  }
}

// ---------------- flash attention (64-kpos tiles, pipelined staging) ----------
// Each XCD owns 8 heads -> per-XCD KV working set ~4 MB ~ L2-resident.
// Q pre-scaled by 0.125*log2e -> exp2(s) directly.
// Pipeline: K double-buffered (issued 1 iter ahead, waited vmcnt(4));
// V single-buffered, issued after PV barrier, waited vmcnt(2) AFTER next
// iter's QK+softmax (latency hides under compute). Raw s_barrier + counted
// vmcnt -- never drain to 0 in the main loop (T3/T4).
// LDS = 16 (K dbuf) + 8 (V) + 16 (p_sh, XOR-swizzled) = 40 KB -> 4 blocks/CU.
__global__ __launch_bounds__(256, 4) void attn_kernel(
    const unsigned short* __restrict__ qb, const unsigned short* __restrict__ kb,
    const unsigned short* __restrict__ vb, unsigned short* __restrict__ ctx) {
  __shared__ __align__(16) unsigned short k_sh[2][64 * 64];  // [kpos][d] dbuf 16 KB
  __shared__ __align__(16) unsigned short vT_sh[64 * 64];    // [d][kpos]      8 KB
  __shared__ __align__(16) unsigned short p_sh[128 * 64];    // [qrow][64] swz 16 KB
  const int bid = blockIdx.x;
  const int xcd = bid & 7, idx = bid >> 3;       // 128 blocks per XCD
  const int bh = xcd * 8 + (idx >> 4);           // 8 heads per XCD
  const int q0 = (idx & 15) * 128;
  const int tid = threadIdx.x;
  const int wv = tid >> 6, lane = tid & 63, qq = lane >> 4, ln = lane & 15;

  // Q as B-fragments: B[k=d][n=qrow], lane n=ln, k=qq*8+j (+32 per kq)
  bf16x8 qf[2][2];
  {
    const unsigned short* qbase = qb + ((size_t)bh * 2048 + q0 + wv * 32) * 64;
#pragma unroll
    for (int rb = 0; rb < 2; ++rb)
#pragma unroll
      for (int kq = 0; kq < 2; ++kq)
        qf[rb][kq] = *(const bf16x8*)(qbase + (rb * 16 + ln) * 64 + kq * 32 + qq * 8);
  }

  // O^T accumulators: D[m=d (nt tiles)][n=qrow (rb tiles)]; lane: qrow=ln, d=qq*4+r
  f32x4 o_acc[2][4];
  float l_i[2] = {0.f, 0.f};                       // per-lane partial row sums
#pragma unroll
  for (int rb = 0; rb < 2; ++rb)
#pragma unroll
    for (int nt = 0; nt < 4; ++nt) o_acc[rb][nt] = f32x4{0.f, 0.f, 0.f, 0.f};

  const unsigned short* kgbase = kb + (size_t)bh * 2048 * 64;
  const unsigned short* vgbase = vb + (size_t)bh * 64 * 2048;
  const int cc0 = wv * 2;                          // this wave's 2 staging chunks

  // stage one 64x64 K tile (8 KB) into dst: 2 global_load_lds per wave
  auto stageK = [&](int kt, unsigned short* dst) {
#pragma unroll
    for (int i = 0; i < 2; ++i) {
      int jp = (cc0 + i) * 64 + lane;              // 0..511
      int row = jp >> 3, c = (jp & 7) ^ (row & 7); // pre-swizzled global source
      async16(kgbase + (size_t)(kt * 64 + row) * 64 + c * 8, dst + (cc0 + i) * 512);
    }
  };
  // stage one 64x64 V^T tile into vT_sh: 2 global_load_lds per wave
  auto stageV = [&](int kt) {
#pragma unroll
    for (int i = 0; i < 2; ++i) {
      int jp = (cc0 + i) * 64 + lane;
      int row = jp >> 3, c = (jp & 7) ^ (row & 7);
      async16(vgbase + (size_t)row * 2048 + kt * 64 + c * 8, vT_sh + (cc0 + i) * 512);
    }
  };

  // prologue: per-wave outstanding after this = K(0)[2], V(0)[2]
  stageK(0, k_sh[0]);
  stageV(0);

  for (int kt = 0; kt < 32; ++kt) {
    const unsigned short* kcur = k_sh[kt & 1];
    // issue K(kt+1); then wait own K(kt) done. Outstanding oldest-first:
    // K(kt)2, V(kt)2, K(kt+1)2 -> vmcnt(4) retires K(kt).
    if (kt < 31) {
      stageK(kt + 1, k_sh[(kt & 1) ^ 1]);
      asm volatile("s_waitcnt vmcnt(4)" ::: "memory");
    } else {
      asm volatile("s_waitcnt vmcnt(2)" ::: "memory");   // no K(32): retire K(31)
    }
    __builtin_amdgcn_s_barrier();                  // K(kt) visible from all waves

    // S^T = K @ Q^T : K-fragments loaded once, both rb accumulated
    f32x4 s_acc[2][4];
#pragma unroll
    for (int rb = 0; rb < 2; ++rb)
#pragma unroll
      for (int ct = 0; ct < 4; ++ct) s_acc[rb][ct] = f32x4{0.f, 0.f, 0.f, 0.f};
    __builtin_amdgcn_s_setprio(1);
#pragma unroll
    for (int ct = 0; ct < 4; ++ct) {
      int row = ct * 16 + ln;
      bf16x8 kf0 = *(const bf16x8*)(kcur + row * 64 + ((0 + qq) ^ (row & 7)) * 8);
      bf16x8 kf1 = *(const bf16x8*)(kcur + row * 64 + ((4 + qq) ^ (row & 7)) * 8);
#pragma unroll
      for (int rb = 0; rb < 2; ++rb) {
        s_acc[rb][ct] = __builtin_amdgcn_mfma_f32_16x16x32_bf16(kf0, qf[rb][0], s_acc[rb][ct], 0, 0, 0);
        s_acc[rb][ct] = __builtin_amdgcn_mfma_f32_16x16x32_bf16(kf1, qf[rb][1], s_acc[rb][ct], 0, 0, 0);
      }
    }
    __builtin_amdgcn_s_setprio(0);

    // exp2 (scores already in log2 domain), pack into p_sh (XOR-swizzled).
    // logical col = ct*16+qq*4 -> 16B slot = ct*2+(qq>>1), half = qq&1;
    // physical slot = logical ^ (row&7). Write/read same-wave rows only.
#pragma unroll
    for (int rb = 0; rb < 2; ++rb) {
      int prow = wv * 32 + rb * 16 + ln;
      int rs = prow & 7;
      float sum = 0.f;
#pragma unroll
      for (int ct = 0; ct < 4; ++ct) {
        float p0 = __builtin_amdgcn_exp2f(s_acc[rb][ct][0]);
        float p1 = __builtin_amdgcn_exp2f(s_acc[rb][ct][1]);
        float p2 = __builtin_amdgcn_exp2f(s_acc[rb][ct][2]);
        float p3 = __builtin_amdgcn_exp2f(s_acc[rb][ct][3]);
        sum += (p0 + p1) + (p2 + p3);
        uint2 pk;
        pk.x = pk2(p0, p1);
        pk.y = pk2(p2, p3);
        *(uint2*)(p_sh + prow * 64 + (((ct * 2 + (qq >> 1)) ^ rs) << 3) + ((qq & 1) << 2)) = pk;
      }
      l_i[rb] += sum;
    }

    // wait own V(kt) (issued end of prev iter; latency hid under QK+softmax),
    // leave K(kt+1) in flight.
    if (kt < 31) asm volatile("s_waitcnt vmcnt(2)" ::: "memory");
    else         asm volatile("s_waitcnt vmcnt(0)" ::: "memory");
    __builtin_amdgcn_s_barrier();                  // V(kt) visible from all waves

    // O^T += V^T @ P^T : A=V^T (m=d), B=P (n=qrow)
#pragma unroll
    for (int kk = 0; kk < 2; ++kk) {
      bf16x8 vf[4], pf[2];
#pragma unroll
      for (int nt = 0; nt < 4; ++nt) {
        int row = nt * 16 + ln;
        vf[nt] = *(const bf16x8*)(vT_sh + row * 64 + ((kk * 4 + qq) ^ (row & 7)) * 8);
      }
#pragma unroll
      for (int rb = 0; rb < 2; ++rb) {
        int row = wv * 32 + rb * 16 + ln;
        pf[rb] = *(const bf16x8*)(p_sh + row * 64 + (((kk * 4 + qq) ^ (row & 7)) << 3));
      }
      __builtin_amdgcn_s_setprio(1);
#pragma unroll
      for (int rb = 0; rb < 2; ++rb)
#pragma unroll
        for (int nt = 0; nt < 4; ++nt)
          o_acc[rb][nt] = __builtin_amdgcn_mfma_f32_16x16x32_bf16(vf[nt], pf[rb], o_acc[rb][nt], 0, 0, 0);
      __builtin_amdgcn_s_setprio(0);
    }
    __builtin_amdgcn_s_barrier();                  // all waves done reading vT_sh
    if (kt < 31) stageV(kt + 1);                   // now safe to overwrite V
  }

  // finalize row sums (cross-quad) then normalize + transpose via p_sh
#pragma unroll
  for (int rb = 0; rb < 2; ++rb) {
    l_i[rb] += __shfl_xor(l_i[rb], 16);
    l_i[rb] += __shfl_xor(l_i[rb], 32);
    float inv = 1.0f / l_i[rb];
    int row = wv * 32 + rb * 16 + ln;
    int rs = row & 7;
#pragma unroll
    for (int nt = 0; nt < 4; ++nt) {
      uint2 pk;
      pk.x = pk2(o_acc[rb][nt][0] * inv, o_acc[rb][nt][1] * inv);
      pk.y = pk2(o_acc[rb][nt][2] * inv, o_acc[rb][nt][3] * inv);
      *(uint2*)(p_sh + row * 64 + (((nt * 2 + (qq >> 1)) ^ rs) << 3) + ((qq & 1) << 2)) = pk;
    }
  }
  // transpose read is same-wave as the writes (tid>>1 stays in this wave's
  // 32-row slice): in-order LDS pipe, no barrier needed.
  {
    const int b = bh >> 4, h = bh & 15;
    int r = tid >> 1, half = tid & 1;
    int rs = r & 7;
    int s = q0 + r;
    size_t gbase = ((size_t)(b * 2048 + s)) * 1024 + h * 64 + half * 32;
    const unsigned short* lsrc = p_sh + r * 64;
#pragma unroll
    for (int j = 0; j < 4; ++j)
      ((ulonglong2*)(ctx + gbase + j * 8))[0] =
          *(const ulonglong2*)(lsrc + (((half * 4 + j) ^ rs) << 3));
  }
}

// ---------------- output GEMM: out[8192,1024] = ctx @ Wo^T + bo (fp32 out) ----------------
// XCD-swizzled 1D grid (512): 1 n-tile per XCD -> 0.25 MB B strip L2-resident.
// Only 2 blocks/CU -> little TLP: double-buffer staging with counted vmcnt
// (raw s_barrier, never drain to 0 in-loop) to hide load latency intra-block.
__global__ __launch_bounds__(256) void gemm_out(
    const unsigned short* __restrict__ ctx, const unsigned short* __restrict__ wo,
    const float* __restrict__ bo, float* __restrict__ out) {
  __shared__ __align__(16) unsigned short As[2][128 * 32];   // 16 KB
  __shared__ __align__(16) unsigned short Bs[2][128 * 32];   // 16 KB
  const int bid = blockIdx.x;
  const int n0 = (bid & 7) * 128;
  const int m0 = (bid >> 3) * 128;
  const int tid = threadIdx.x;
  const int wv = tid >> 6, lane = tid & 63, qq = lane >> 4, ln = lane & 15;
  const int wm = wv & 1, wn = wv >> 1;
  const int K = 1024;

  f32x4 acc[4][4];
#pragma unroll
  for (int i = 0; i < 4; ++i)
#pragma unroll
    for (int j = 0; j < 4; ++j) acc[i][j] = f32x4{0.f, 0.f, 0.f, 0.f};

  auto stage = [&](int t, int buf) {               // 4 loads per wave
#pragma unroll
    for (int i = 0; i < 2; ++i) {
      int cc = wv * 2 + i;
      int jp = cc * 64 + lane;
      int row = jp >> 2, cp = jp & 3;
      int c = cp ^ ((row >> 1) & 3);
      async16(ctx + (size_t)(m0 + row) * K + t * 32 + c * 8, As[buf] + cc * 512);
      async16(wo  + (size_t)(n0 + row) * K + t * 32 + c * 8, Bs[buf] + cc * 512);
    }
  };

  stage(0, 0);
  for (int t = 0; t < 32; ++t) {
    const int cur = t & 1;
    if (t < 31) {
      stage(t + 1, cur ^ 1);
      // outstanding: stage(t)[4] + stage(t+1)[4] -> retire stage(t) only
      asm volatile("s_waitcnt vmcnt(4)" ::: "memory");
    } else {
      asm volatile("s_waitcnt vmcnt(0)" ::: "memory");
    }
    __builtin_amdgcn_s_barrier();                  // buf[cur] visible from all waves

    bf16x8 af[4], bf[4];
#pragma unroll
    for (int i = 0; i < 4; ++i) {
      int row = wm * 64 + i * 16 + ln;
      af[i] = *(const bf16x8*)(As[cur] + row * 32 + (qq ^ ((row >> 1) & 3)) * 8);
    }
#pragma unroll
    for (int j = 0; j < 4; ++j) {
      int row = wn * 64 + j * 16 + ln;
      bf[j] = *(const bf16x8*)(Bs[cur] + row * 32 + (qq ^ ((row >> 1) & 3)) * 8);
    }
#pragma unroll
    for (int i = 0; i < 4; ++i)
#pragma unroll
      for (int j = 0; j < 4; ++j)
        acc[i][j] = __builtin_amdgcn_mfma_f32_16x16x32_bf16(af[i], bf[j], acc[i][j], 0, 0, 0);
    __builtin_amdgcn_s_barrier();                  // done reading buf[cur];
                                                   // next iter overwrites buf[cur^1]... then buf[cur]
  }

#pragma unroll
  for (int j = 0; j < 4; ++j) {
    int n = n0 + wn * 64 + j * 16 + ln;
    float bsv = bo[n];
#pragma unroll
    for (int i = 0; i < 4; ++i) {
#pragma unroll
      for (int r = 0; r < 4; ++r) {
        int m = m0 + wm * 64 + i * 16 + qq * 4 + r;
        out[(size_t)m * 1024 + n] = acc[i][j][r] + bsv;
      }
    }
  }
}

// ---------------- launch ----------------
extern "C" void kernel_launch(void* const* d_in, const int* in_sizes, int n_in,
                              void* d_out, int out_size, void* d_ws, size_t ws_size,
                              hipStream_t stream) {
  const float* x  = (const float*)d_in[0];
  const float* Wq = (const float*)d_in[1];
  const float* bq = (const float*)d_in[2];
  const float* Wk = (const float*)d_in[3];
  const float* bk = (const float*)d_in[4];
  const float* Wv = (const float*)d_in[5];
  const float* bv = (const float*)d_in[6];
  const float* Wo = (const float*)d_in[7];
  const float* bo = (const float*)d_in[8];
  float* out = (float*)d_out;

  char* ws = (char*)d_ws;
  unsigned short* xb   = (unsigned short*)(ws);                      // 16M
  unsigned short* ctxb = (unsigned short*)(ws);                      // reuse
  unsigned short* qb   = (unsigned short*)(ws + ((size_t)16 << 20)); // 16M
  unsigned short* kbuf = (unsigned short*)(ws + ((size_t)32 << 20)); // 16M
  unsigned short* vbuf = (unsigned short*)(ws + ((size_t)48 << 20)); // 16M
  unsigned short* wqkv = (unsigned short*)(ws + ((size_t)64 << 20)); // 6M
  unsigned short* wo   = (unsigned short*)(ws + ((size_t)70 << 20)); // 2M

  cast_all<<<12288, 256, 0, stream>>>(x, Wq, Wk, Wv, Wo, xb, wqkv, wo);

  gemm_qkv<<<1536, 256, 0, stream>>>(xb, wqkv, bq, bk, bv, qb, kbuf, vbuf);
  attn_kernel<<<1024, 256, 0, stream>>>(qb, kbuf, vbuf, ctxb);
  gemm_out<<<512, 256, 0, stream>>>(ctxb, wo, bo, out);
}